// Round 1
// baseline (249.701 us; speedup 1.0000x reference)
//
#include <hip/hip_runtime.h>

#define BB 4
#define SS 2048
#define EE 512
#define HH 8
#define DHH 8
#define DVV 64   // H*DHH

#define NEG (-1e30f)

// ---------------- Kernel A: QKV projections, register-tiled GEMM ----------
// C[row, col] = sum_e X[row,e] * W[col/8, e, col%8];  X:[8192,512], C:[8192,64]
// grid (8192/64, 3), block 256. Thread tile 4x4, K-tile 64. (unchanged)
__global__ __launch_bounds__(256)
void proj_kernel(const float* __restrict__ q, const float* __restrict__ k,
                 const float* __restrict__ v,
                 const float* __restrict__ Wq, const float* __restrict__ Wk,
                 const float* __restrict__ Wv,
                 float* __restrict__ Qp, float* __restrict__ Kp,
                 float* __restrict__ Vp)
{
  const float* x; const float* W; float* outp;
  if (blockIdx.y == 0)      { x = q; W = Wq; outp = Qp; }
  else if (blockIdx.y == 1) { x = k; W = Wk; outp = Kp; }
  else                      { x = v; W = Wv; outp = Vp; }

  __shared__ float Xs[64][68];   // [k][row]
  __shared__ float Ws[64][68];   // [k][col]

  int t = threadIdx.x;
  int row0 = blockIdx.x * 64;
  int tr = t >> 4;               // 0..15 -> rows 4*tr..4*tr+3
  int tc = t & 15;               // 0..15 -> cols 4*tc..4*tc+3

  float acc[4][4];
  #pragma unroll
  for (int i = 0; i < 4; i++)
    #pragma unroll
    for (int j = 0; j < 4; j++) acc[i][j] = 0.f;

  for (int kt = 0; kt < EE/64; kt++) {
    __syncthreads();
    // stage X tile transposed: Xs[k][row] = x[row0+row][kt*64+k]
    {
      int row = t >> 2;
      #pragma unroll
      for (int it = 0; it < 4; it++) {
        int kq = 4*it + (t & 3);
        float4 vv = *(const float4*)(x + (size_t)(row0+row)*EE + kt*64 + 4*kq);
        Xs[4*kq+0][row] = vv.x;
        Xs[4*kq+1][row] = vv.y;
        Xs[4*kq+2][row] = vv.z;
        Xs[4*kq+3][row] = vv.w;
      }
    }
    // stage W tile: Ws[k][8h+d] = W[h][kt*64+k][d]
    #pragma unroll
    for (int it = 0; it < 4; it++) {
      int lin = t + 256*it;          // 0..1023
      int kk  = lin >> 4;            // 0..63
      int rem = lin & 15;
      int h   = rem >> 1;
      int dq  = rem & 1;
      float4 vv = *(const float4*)(W + (size_t)h*EE*DHH + (size_t)(kt*64+kk)*DHH + dq*4);
      *(float4*)&Ws[kk][h*8 + dq*4] = vv;
    }
    __syncthreads();

    #pragma unroll 8
    for (int kk = 0; kk < 64; kk++) {
      float4 a = *(const float4*)&Xs[kk][4*tr];
      float4 bq = *(const float4*)&Ws[kk][4*tc];
      float av[4] = {a.x, a.y, a.z, a.w};
      float bv[4] = {bq.x, bq.y, bq.z, bq.w};
      #pragma unroll
      for (int i = 0; i < 4; i++)
        #pragma unroll
        for (int j = 0; j < 4; j++) acc[i][j] += av[i] * bv[j];
    }
  }

  int h = tc >> 1, dbase = (tc & 1) * 4;
  #pragma unroll
  for (int i = 0; i < 4; i++) {
    int row = row0 + 4*tr + i;
    int b = row >> 11, s = row & (SS - 1);
    float4 vv; vv.x = acc[i][0]; vv.y = acc[i][1]; vv.z = acc[i][2]; vv.w = acc[i][3];
    *(float4*)(outp + (((size_t)b*HH + h)*SS + s)*DHH + dbase) = vv;
  }
}

// ---------------- Kernel B: causal flash attention, v2 --------------------
// grid (16, H, B), block 256; q-tile pair (bx, 31-bx) per block (load balance).
// Thread tile: 8 rows (rg=t&7) x 4 col slots (cs=t>>3, c=cs+32j) ->
//   K/V LDS reads amortized 4x vs v1 (16 b128/lane/tile vs 64).
// Max-free fused softmax: q pre-scaled by scale*log2e, p = exp2(q.k) directly,
//   single fused QK+exp+PV loop, no per-tile max/rescale. Valid because
//   fp32 range >> score range; wave-uniform overflow guard (never fires on
//   this data) keeps it correct for arbitrary inputs.
// K/V double-buffered: global loads for kt+1 issue before compute of kt,
//   LDS write after -> 1 barrier/tile, HBM/L2 latency hidden under compute.
__global__ __launch_bounds__(256, 2)
void attn_kernel(const float* __restrict__ Qp, const float* __restrict__ Kp,
                 const float* __restrict__ Vp, float* __restrict__ O)
{
  int bx = blockIdx.x, h = blockIdx.y, b = blockIdx.z;
  const float* Qh = Qp + (((size_t)b*HH + h)*SS)*DHH;
  const float* Kh = Kp + (((size_t)b*HH + h)*SS)*DHH;
  const float* Vh = Vp + (((size_t)b*HH + h)*SS)*DHH;

  __shared__ float Ks[2][128*DHH];   // 2 x 4 KiB
  __shared__ float Vs[2][128*DHH];   // 2 x 4 KiB
  __shared__ float Ps[4*64*10];      // 10 KiB cross-wave partials

  const int t  = threadIdx.x;
  const int rg = t & 7;              // rows 8*rg .. 8*rg+7 of the q-tile
  const int cs = t >> 3;             // 0..31 col slot; cols c = cs + 32*j
  // 1/sqrt(8) * log2(e): p = exp2(s') == exp((q.k)/sqrt(8))
  const float SCL = 0.35355339059327373f * 1.4426950408889634f;

  int cur = 0;

  for (int pass = 0; pass < 2; pass++) {
    const int qb = (pass == 0) ? bx : (31 - bx);
    const int row0t = qb*64 + 8*rg;

    // q rows, pre-scaled into log2 domain
    float qreg[8][8];
    #pragma unroll
    for (int i = 0; i < 8; i++) {
      const float* qp = Qh + (size_t)(row0t + i) * DHH;
      float4 a = *(const float4*)qp;
      float4 c = *(const float4*)(qp + 4);
      qreg[i][0] = a.x*SCL; qreg[i][1] = a.y*SCL;
      qreg[i][2] = a.z*SCL; qreg[i][3] = a.w*SCL;
      qreg[i][4] = c.x*SCL; qreg[i][5] = c.y*SCL;
      qreg[i][6] = c.z*SCL; qreg[i][7] = c.w*SCL;
    }

    float M = 0.f, negM = 0.f;       // wave-uniform log2 shift (stays 0 in practice)
    float l[8];
    float o[8][8];
    #pragma unroll
    for (int i = 0; i < 8; i++) {
      l[i] = 0.f;
      #pragma unroll
      for (int d = 0; d < 8; d++) o[i][d] = 0.f;
    }

    // stage K/V tile 0 of this pass (safe: all waves crossed the Ps barrier
    // of the previous pass before any compute-read of these buffers ended)
    ((float4*)Ks[cur])[t] = ((const float4*)Kh)[t];
    ((float4*)Vs[cur])[t] = ((const float4*)Vh)[t];

    const int ktd = qb >> 1;
    for (int kt = 0; kt <= ktd; kt++) {
      __syncthreads();               // buf[cur] visible to all waves
      float4 kstg, vstg;
      const bool pre = (kt < ktd);
      if (pre) {                     // issue next-tile loads; land after compute
        kstg = ((const float4*)(Kh + (size_t)(kt+1)*128*DHH))[t];
        vstg = ((const float4*)(Vh + (size_t)(kt+1)*128*DHH))[t];
      }
      const float* KsC = Ks[cur];
      const float* VsC = Vs[cur];

      if (kt < ktd) {
        // ---- full tile: every (row,col) valid, fused QK+exp+PV ----
        #pragma unroll
        for (int j = 0; j < 4; j++) {
          const int c8 = (cs + 32*j) * DHH;
          float4 k0 = *(const float4*)&KsC[c8];
          float4 k1 = *(const float4*)&KsC[c8 + 4];
          float4 v0 = *(const float4*)&VsC[c8];
          float4 v1 = *(const float4*)&VsC[c8 + 4];
          #pragma unroll
          for (int i = 0; i < 8; i++) {
            float s = fmaf(qreg[i][0], k0.x, negM);
            s = fmaf(qreg[i][1], k0.y, s);
            s = fmaf(qreg[i][2], k0.z, s);
            s = fmaf(qreg[i][3], k0.w, s);
            s = fmaf(qreg[i][4], k1.x, s);
            s = fmaf(qreg[i][5], k1.y, s);
            s = fmaf(qreg[i][6], k1.z, s);
            s = fmaf(qreg[i][7], k1.w, s);
            const float p = __builtin_amdgcn_exp2f(s);
            l[i] += p;
            o[i][0] = fmaf(p, v0.x, o[i][0]);
            o[i][1] = fmaf(p, v0.y, o[i][1]);
            o[i][2] = fmaf(p, v0.z, o[i][2]);
            o[i][3] = fmaf(p, v0.w, o[i][3]);
            o[i][4] = fmaf(p, v1.x, o[i][4]);
            o[i][5] = fmaf(p, v1.y, o[i][5]);
            o[i][6] = fmaf(p, v1.z, o[i][6]);
            o[i][7] = fmaf(p, v1.w, o[i][7]);
          }
        }
      } else {
        // ---- diagonal tile: per-element causal mask; masked -> p = 0 ----
        #pragma unroll
        for (int j = 0; j < 4; j++) {
          const int c  = cs + 32*j;
          const int cg = kt*128 + c;
          if (cg > row0t + 7) break;       // monotone in j (per-lane)
          const int c8 = c * DHH;
          float4 k0 = *(const float4*)&KsC[c8];
          float4 k1 = *(const float4*)&KsC[c8 + 4];
          float4 v0 = *(const float4*)&VsC[c8];
          float4 v1 = *(const float4*)&VsC[c8 + 4];
          #pragma unroll
          for (int i = 0; i < 8; i++) {
            float s = fmaf(qreg[i][0], k0.x, negM);
            s = fmaf(qreg[i][1], k0.y, s);
            s = fmaf(qreg[i][2], k0.z, s);
            s = fmaf(qreg[i][3], k0.w, s);
            s = fmaf(qreg[i][4], k1.x, s);
            s = fmaf(qreg[i][5], k1.y, s);
            s = fmaf(qreg[i][6], k1.z, s);
            s = fmaf(qreg[i][7], k1.w, s);
            s = (cg > row0t + i) ? NEG : s;      // exp2(-1e30) == 0
            const float p = __builtin_amdgcn_exp2f(s);
            l[i] += p;
            o[i][0] = fmaf(p, v0.x, o[i][0]);
            o[i][1] = fmaf(p, v0.y, o[i][1]);
            o[i][2] = fmaf(p, v0.z, o[i][2]);
            o[i][3] = fmaf(p, v0.w, o[i][3]);
            o[i][4] = fmaf(p, v1.x, o[i][4]);
            o[i][5] = fmaf(p, v1.y, o[i][5]);
            o[i][6] = fmaf(p, v1.z, o[i][6]);
            o[i][7] = fmaf(p, v1.w, o[i][7]);
          }
        }
      }

      // overflow guard: l <= ncols * 2^(smax - M); this data has smax ~ 15,
      // so 1e18 (~2^60) never trips. Wave-uniform -> M identical across the
      // wave, which makes the butterfly merge below pure adds.
      float lm = fmaxf(fmaxf(fmaxf(l[0], l[1]), fmaxf(l[2], l[3])),
                       fmaxf(fmaxf(l[4], l[5]), fmaxf(l[6], l[7])));
      if (__any(lm > 1e18f)) {
        const float dsc = 5.421010862427522e-20f;   // 2^-64
        #pragma unroll
        for (int i = 0; i < 8; i++) {
          l[i] *= dsc;
          #pragma unroll
          for (int d = 0; d < 8; d++) o[i][d] *= dsc;
        }
        M += 64.f; negM = -M;
      }

      if (pre) {                     // write staged tile kt+1 (waitcnt here)
        ((float4*)Ks[cur ^ 1])[t] = kstg;
        ((float4*)Vs[cur ^ 1])[t] = vstg;
        cur ^= 1;
      }
    }

    // intra-wave butterfly: partners t^8,t^16,t^32 share rows (same rg) and
    // the same wave-uniform M -> merge is a plain sum.
    #pragma unroll
    for (int i = 0; i < 8; i++) {
      l[i] += __shfl_xor(l[i], 8);
      #pragma unroll
      for (int d = 0; d < 8; d++) o[i][d] += __shfl_xor(o[i][d], 8);
      l[i] += __shfl_xor(l[i], 16);
      #pragma unroll
      for (int d = 0; d < 8; d++) o[i][d] += __shfl_xor(o[i][d], 16);
      l[i] += __shfl_xor(l[i], 32);
      #pragma unroll
      for (int d = 0; d < 8; d++) o[i][d] += __shfl_xor(o[i][d], 32);
    }

    // one partial per wave per row; lanes 0..7 of each wave write (rg == lane)
    if ((t & 56) == 0) {
      const int w = t >> 6;
      #pragma unroll
      for (int i = 0; i < 8; i++) {
        float* ps = &Ps[(size_t)(w*64 + 8*rg + i) * 10];
        ps[0] = M; ps[1] = l[i];
        #pragma unroll
        for (int d = 0; d < 8; d++) ps[2 + d] = o[i][d];
      }
    }
    __syncthreads();

    // cross-wave: general M-aware merge of 4 partials, normalize, store
    if (t < 64) {
      float Mx = NEG, L = 0.f;
      float O8[8] = {0,0,0,0,0,0,0,0};
      #pragma unroll
      for (int ww = 0; ww < 4; ww++) {
        const float* ps = &Ps[(size_t)(ww*64 + t) * 10];
        const float mo = ps[0], lo = ps[1];
        const float mm = fmaxf(Mx, mo);
        const float a1 = __builtin_amdgcn_exp2f(Mx - mm);
        const float a2 = __builtin_amdgcn_exp2f(mo - mm);
        L = L*a1 + lo*a2;
        #pragma unroll
        for (int d = 0; d < 8; d++) O8[d] = O8[d]*a1 + ps[2 + d]*a2;
        Mx = mm;
      }
      const float inv = 1.0f / L;
      const int qrow = qb*64 + t;
      float* dst = O + ((size_t)b*SS + qrow)*DVV + h*DHH;
      float4 w0, w1;
      w0.x = O8[0]*inv; w0.y = O8[1]*inv; w0.z = O8[2]*inv; w0.w = O8[3]*inv;
      w1.x = O8[4]*inv; w1.y = O8[5]*inv; w1.z = O8[6]*inv; w1.w = O8[7]*inv;
      *(float4*)dst = w0;
      *(float4*)(dst + 4) = w1;
    }
    // no trailing barrier needed: next pass touches Ks/Vs (not Ps) before its
    // first kt-barrier, and all compute reads of Ks/Vs ended before the Ps
    // barrier above.
  }
}

// ---------------- Kernel C: output projection, register-tiled GEMM --------
// out[row,e] = sum_d O[row,d]*Wo[d,e] + bo[e]; grid (8192/64, 512/128), block 256.
// (unchanged)
__global__ __launch_bounds__(256)
void outproj_kernel(const float* __restrict__ Oin, const float* __restrict__ Wo,
                    const float* __restrict__ bo, float* __restrict__ out)
{
  __shared__ float Os[64][68];   // [k][row] transposed
  int t = threadIdx.x;
  int row0 = blockIdx.x * 64;
  int col0 = blockIdx.y * 128;

  {
    int row = t >> 2;
    #pragma unroll
    for (int it = 0; it < 4; it++) {
      int kq = 4*it + (t & 3);
      float4 vv = *(const float4*)(Oin + (size_t)(row0+row)*DVV + 4*kq);
      Os[4*kq+0][row] = vv.x;
      Os[4*kq+1][row] = vv.y;
      Os[4*kq+2][row] = vv.z;
      Os[4*kq+3][row] = vv.w;
    }
  }
  __syncthreads();

  int rg = t >> 5;               // 0..7 -> rows 8*rg..8*rg+7
  int tc = t & 31;               // cols col0 + 4*tc .. +3
  const float* wp = Wo + col0 + 4*tc;
  float4 b4 = *(const float4*)(bo + col0 + 4*tc);

  float acc[8][4];
  #pragma unroll
  for (int r = 0; r < 8; r++) {
    acc[r][0] = b4.x; acc[r][1] = b4.y; acc[r][2] = b4.z; acc[r][3] = b4.w;
  }

  #pragma unroll 8
  for (int k = 0; k < DVV; k++) {
    float4 w = *(const float4*)(wp + (size_t)k*EE);   // coalesced, L2-hot
    float xr[8];
    *(float4*)&xr[0] = *(const float4*)&Os[k][8*rg];
    *(float4*)&xr[4] = *(const float4*)&Os[k][8*rg + 4];
    #pragma unroll
    for (int r = 0; r < 8; r++) {
      acc[r][0] += xr[r]*w.x;
      acc[r][1] += xr[r]*w.y;
      acc[r][2] += xr[r]*w.z;
      acc[r][3] += xr[r]*w.w;
    }
  }

  #pragma unroll
  for (int r = 0; r < 8; r++) {
    int row = row0 + 8*rg + r;
    float4 vv; vv.x = acc[r][0]; vv.y = acc[r][1]; vv.z = acc[r][2]; vv.w = acc[r][3];
    *(float4*)(out + (size_t)row*EE + col0 + 4*tc) = vv;
  }
}

extern "C" void kernel_launch(void* const* d_in, const int* in_sizes, int n_in,
                              void* d_out, int out_size, void* d_ws, size_t ws_size,
                              hipStream_t stream) {
  // Size-based input identification: q/k/v=4194304, Wq/Wk/Wv/Wo=32768 in dict
  // order, bo=512. padding_mask (16777216) / decoder_mask (1) skipped.
  const void* qkv[3] = {nullptr, nullptr, nullptr};
  const void* Wlist[4] = {nullptr, nullptr, nullptr, nullptr};
  const void* bo = nullptr;
  int nqkv = 0, nw = 0;
  for (int i = 0; i < n_in; i++) {
    int sz = in_sizes[i];
    if (sz == BB*SS*EE)            { if (nqkv < 3) qkv[nqkv] = d_in[i]; nqkv++; }
    else if (sz == HH*EE*DHH)      { if (nw < 4) Wlist[nw] = d_in[i]; nw++; }
    else if (sz == EE)             { bo = d_in[i]; }
  }
  float* out = (float*)d_out;   // reference output dtype is float32

  // workspace (f32): Qp/Kp/Vp [B,H,S,8] (2MB each), O [B,S,64] (2MB)
  float* Qp = (float*)d_ws;
  float* Kp = Qp + (size_t)BB*HH*SS*DHH;
  float* Vp = Kp + (size_t)BB*HH*SS*DHH;
  float* O  = Vp + (size_t)BB*HH*SS*DHH;

  dim3 gA(BB*SS/64, 3, 1);
  proj_kernel<<<gA, 256, 0, stream>>>((const float*)qkv[0], (const float*)qkv[1],
                                      (const float*)qkv[2],
                                      (const float*)Wlist[0], (const float*)Wlist[1],
                                      (const float*)Wlist[2], Qp, Kp, Vp);

  dim3 gB(16, HH, BB);
  attn_kernel<<<gB, 256, 0, stream>>>(Qp, Kp, Vp, O);

  dim3 gC(BB*SS/64, EE/128, 1);
  outproj_kernel<<<gC, 256, 0, stream>>>(O, (const float*)Wlist[3],
                                         (const float*)bo, out);
}

// Round 2
// 220.721 us; speedup vs baseline: 1.1313x; 1.1313x over previous
//
#include <hip/hip_runtime.h>

#define BB 4
#define SS 2048
#define EE 512
#define HH 8
#define DHH 8
#define DVV 64   // H*DHH

#define NEG (-1e30f)

// ---------------- Kernel A: QKV projections, register-tiled GEMM ----------
// C[row, col] = sum_e X[row,e] * W[col/8, e, col%8];  X:[8192,512], C:[8192,64]
// grid (8192/64, 3), block 256. Thread tile 4x4, K-tile 64. (unchanged)
__global__ __launch_bounds__(256)
void proj_kernel(const float* __restrict__ q, const float* __restrict__ k,
                 const float* __restrict__ v,
                 const float* __restrict__ Wq, const float* __restrict__ Wk,
                 const float* __restrict__ Wv,
                 float* __restrict__ Qp, float* __restrict__ Kp,
                 float* __restrict__ Vp)
{
  const float* x; const float* W; float* outp;
  if (blockIdx.y == 0)      { x = q; W = Wq; outp = Qp; }
  else if (blockIdx.y == 1) { x = k; W = Wk; outp = Kp; }
  else                      { x = v; W = Wv; outp = Vp; }

  __shared__ float Xs[64][68];   // [k][row]
  __shared__ float Ws[64][68];   // [k][col]

  int t = threadIdx.x;
  int row0 = blockIdx.x * 64;
  int tr = t >> 4;               // 0..15 -> rows 4*tr..4*tr+3
  int tc = t & 15;               // 0..15 -> cols 4*tc..4*tc+3

  float acc[4][4];
  #pragma unroll
  for (int i = 0; i < 4; i++)
    #pragma unroll
    for (int j = 0; j < 4; j++) acc[i][j] = 0.f;

  for (int kt = 0; kt < EE/64; kt++) {
    __syncthreads();
    // stage X tile transposed: Xs[k][row] = x[row0+row][kt*64+k]
    {
      int row = t >> 2;
      #pragma unroll
      for (int it = 0; it < 4; it++) {
        int kq = 4*it + (t & 3);
        float4 vv = *(const float4*)(x + (size_t)(row0+row)*EE + kt*64 + 4*kq);
        Xs[4*kq+0][row] = vv.x;
        Xs[4*kq+1][row] = vv.y;
        Xs[4*kq+2][row] = vv.z;
        Xs[4*kq+3][row] = vv.w;
      }
    }
    // stage W tile: Ws[k][8h+d] = W[h][kt*64+k][d]
    #pragma unroll
    for (int it = 0; it < 4; it++) {
      int lin = t + 256*it;          // 0..1023
      int kk  = lin >> 4;            // 0..63
      int rem = lin & 15;
      int h   = rem >> 1;
      int dq  = rem & 1;
      float4 vv = *(const float4*)(W + (size_t)h*EE*DHH + (size_t)(kt*64+kk)*DHH + dq*4);
      *(float4*)&Ws[kk][h*8 + dq*4] = vv;
    }
    __syncthreads();

    #pragma unroll 8
    for (int kk = 0; kk < 64; kk++) {
      float4 a = *(const float4*)&Xs[kk][4*tr];
      float4 bq = *(const float4*)&Ws[kk][4*tc];
      float av[4] = {a.x, a.y, a.z, a.w};
      float bv[4] = {bq.x, bq.y, bq.z, bq.w};
      #pragma unroll
      for (int i = 0; i < 4; i++)
        #pragma unroll
        for (int j = 0; j < 4; j++) acc[i][j] += av[i] * bv[j];
    }
  }

  int h = tc >> 1, dbase = (tc & 1) * 4;
  #pragma unroll
  for (int i = 0; i < 4; i++) {
    int row = row0 + 4*tr + i;
    int b = row >> 11, s = row & (SS - 1);
    float4 vv; vv.x = acc[i][0]; vv.y = acc[i][1]; vv.z = acc[i][2]; vv.w = acc[i][3];
    *(float4*)(outp + (((size_t)b*HH + h)*SS + s)*DHH + dbase) = vv;
  }
}

// ---------------- Kernel B: causal flash attention, v3 --------------------
// grid (16, H, B), block 256; q-tile pair (bx, 31-bx) per block (load balance).
// Thread tile: 4 rows (rg=t&15) x 8 col slots (cs=t>>4, c=cs+16j).
//   v2's 8x4 tile spilled (VGPR 128, WRITE_SIZE 25.8MB scratch); 4x8 fits:
//   qreg[4][8]+o[4][8]+l[4]+frags ~ 105 VGPR, zero spill, 32 b128/lane/tile.
// Max-free fused softmax: q pre-scaled by scale*log2e, p = exp2(q.k) directly,
//   single fused QK+exp+PV loop, no per-tile max/rescale. Wave-uniform
//   overflow guard (never fires on this data) keeps it exact for any input.
// K/V double-buffered: global loads for kt+1 issue before compute of kt,
//   LDS write after -> 1 barrier/tile, HBM/L2 latency hidden under compute.
__global__ __launch_bounds__(256, 2)
void attn_kernel(const float* __restrict__ Qp, const float* __restrict__ Kp,
                 const float* __restrict__ Vp, float* __restrict__ O)
{
  int bx = blockIdx.x, h = blockIdx.y, b = blockIdx.z;
  const float* Qh = Qp + (((size_t)b*HH + h)*SS)*DHH;
  const float* Kh = Kp + (((size_t)b*HH + h)*SS)*DHH;
  const float* Vh = Vp + (((size_t)b*HH + h)*SS)*DHH;

  __shared__ float Ks[2][128*DHH];   // 2 x 4 KiB
  __shared__ float Vs[2][128*DHH];   // 2 x 4 KiB
  __shared__ float Ps[4*64*10];      // 10 KiB cross-wave partials

  const int t  = threadIdx.x;
  const int rg = t & 15;             // rows 4*rg .. 4*rg+3 of the q-tile
  const int cs = t >> 4;             // 0..15 col slot; cols c = cs + 16*j
  // 1/sqrt(8) * log2(e): p = exp2(s') == exp((q.k)/sqrt(8))
  const float SCL = 0.35355339059327373f * 1.4426950408889634f;

  int cur = 0;

  for (int pass = 0; pass < 2; pass++) {
    const int qb = (pass == 0) ? bx : (31 - bx);
    const int row0t = qb*64 + 4*rg;

    // q rows, pre-scaled into log2 domain
    float qreg[4][8];
    #pragma unroll
    for (int i = 0; i < 4; i++) {
      const float* qp = Qh + (size_t)(row0t + i) * DHH;
      float4 a = *(const float4*)qp;
      float4 c = *(const float4*)(qp + 4);
      qreg[i][0] = a.x*SCL; qreg[i][1] = a.y*SCL;
      qreg[i][2] = a.z*SCL; qreg[i][3] = a.w*SCL;
      qreg[i][4] = c.x*SCL; qreg[i][5] = c.y*SCL;
      qreg[i][6] = c.z*SCL; qreg[i][7] = c.w*SCL;
    }

    float M = 0.f, negM = 0.f;       // wave-uniform log2 shift (stays 0 in practice)
    float l[4];
    float o[4][8];
    #pragma unroll
    for (int i = 0; i < 4; i++) {
      l[i] = 0.f;
      #pragma unroll
      for (int d = 0; d < 8; d++) o[i][d] = 0.f;
    }

    // stage K/V tile 0 of this pass (safe: all waves crossed the Ps barrier
    // of the previous pass before any compute-read of these buffers ended)
    ((float4*)Ks[cur])[t] = ((const float4*)Kh)[t];
    ((float4*)Vs[cur])[t] = ((const float4*)Vh)[t];

    const int ktd = qb >> 1;
    for (int kt = 0; kt <= ktd; kt++) {
      __syncthreads();               // buf[cur] visible to all waves
      float4 kstg, vstg;
      const bool pre = (kt < ktd);
      if (pre) {                     // issue next-tile loads; land after compute
        kstg = ((const float4*)(Kh + (size_t)(kt+1)*128*DHH))[t];
        vstg = ((const float4*)(Vh + (size_t)(kt+1)*128*DHH))[t];
      }
      const float* KsC = Ks[cur];
      const float* VsC = Vs[cur];

      if (kt < ktd) {
        // ---- full tile: every (row,col) valid, fused QK+exp+PV ----
        #pragma unroll
        for (int j = 0; j < 8; j++) {
          const int c8 = (cs + 16*j) * DHH;
          float4 k0 = *(const float4*)&KsC[c8];
          float4 k1 = *(const float4*)&KsC[c8 + 4];
          float4 v0 = *(const float4*)&VsC[c8];
          float4 v1 = *(const float4*)&VsC[c8 + 4];
          #pragma unroll
          for (int i = 0; i < 4; i++) {
            float s = fmaf(qreg[i][0], k0.x, negM);
            s = fmaf(qreg[i][1], k0.y, s);
            s = fmaf(qreg[i][2], k0.z, s);
            s = fmaf(qreg[i][3], k0.w, s);
            s = fmaf(qreg[i][4], k1.x, s);
            s = fmaf(qreg[i][5], k1.y, s);
            s = fmaf(qreg[i][6], k1.z, s);
            s = fmaf(qreg[i][7], k1.w, s);
            const float p = __builtin_amdgcn_exp2f(s);
            l[i] += p;
            o[i][0] = fmaf(p, v0.x, o[i][0]);
            o[i][1] = fmaf(p, v0.y, o[i][1]);
            o[i][2] = fmaf(p, v0.z, o[i][2]);
            o[i][3] = fmaf(p, v0.w, o[i][3]);
            o[i][4] = fmaf(p, v1.x, o[i][4]);
            o[i][5] = fmaf(p, v1.y, o[i][5]);
            o[i][6] = fmaf(p, v1.z, o[i][6]);
            o[i][7] = fmaf(p, v1.w, o[i][7]);
          }
        }
      } else {
        // ---- diagonal tile: per-element causal mask; masked -> p = 0 ----
        #pragma unroll
        for (int j = 0; j < 8; j++) {
          const int c  = cs + 16*j;
          const int cg = kt*128 + c;
          if (cg > row0t + 3) break;       // monotone in j (per-lane)
          const int c8 = c * DHH;
          float4 k0 = *(const float4*)&KsC[c8];
          float4 k1 = *(const float4*)&KsC[c8 + 4];
          float4 v0 = *(const float4*)&VsC[c8];
          float4 v1 = *(const float4*)&VsC[c8 + 4];
          #pragma unroll
          for (int i = 0; i < 4; i++) {
            float s = fmaf(qreg[i][0], k0.x, negM);
            s = fmaf(qreg[i][1], k0.y, s);
            s = fmaf(qreg[i][2], k0.z, s);
            s = fmaf(qreg[i][3], k0.w, s);
            s = fmaf(qreg[i][4], k1.x, s);
            s = fmaf(qreg[i][5], k1.y, s);
            s = fmaf(qreg[i][6], k1.z, s);
            s = fmaf(qreg[i][7], k1.w, s);
            s = (cg > row0t + i) ? NEG : s;      // exp2(-1e30) == 0
            const float p = __builtin_amdgcn_exp2f(s);
            l[i] += p;
            o[i][0] = fmaf(p, v0.x, o[i][0]);
            o[i][1] = fmaf(p, v0.y, o[i][1]);
            o[i][2] = fmaf(p, v0.z, o[i][2]);
            o[i][3] = fmaf(p, v0.w, o[i][3]);
            o[i][4] = fmaf(p, v1.x, o[i][4]);
            o[i][5] = fmaf(p, v1.y, o[i][5]);
            o[i][6] = fmaf(p, v1.z, o[i][6]);
            o[i][7] = fmaf(p, v1.w, o[i][7]);
          }
        }
      }

      // overflow guard: l <= ncols * 2^(smax - M); this data has smax ~ 15,
      // so 1e18 (~2^60) never trips. Wave-uniform -> M identical across the
      // wave, which keeps the butterfly merge below a plain sum.
      float lm = fmaxf(fmaxf(l[0], l[1]), fmaxf(l[2], l[3]));
      if (__any(lm > 1e18f)) {
        const float dsc = 5.421010862427522e-20f;   // 2^-64
        #pragma unroll
        for (int i = 0; i < 4; i++) {
          l[i] *= dsc;
          #pragma unroll
          for (int d = 0; d < 8; d++) o[i][d] *= dsc;
        }
        M += 64.f; negM = -M;
      }

      if (pre) {                     // write staged tile kt+1 (waitcnt here)
        ((float4*)Ks[cur ^ 1])[t] = kstg;
        ((float4*)Vs[cur ^ 1])[t] = vstg;
        cur ^= 1;
      }
    }

    // intra-wave butterfly: partners t^16,t^32 share rows (same rg) and the
    // same wave-uniform M -> merge is a plain sum.
    #pragma unroll
    for (int i = 0; i < 4; i++) {
      l[i] += __shfl_xor(l[i], 16);
      #pragma unroll
      for (int d = 0; d < 8; d++) o[i][d] += __shfl_xor(o[i][d], 16);
      l[i] += __shfl_xor(l[i], 32);
      #pragma unroll
      for (int d = 0; d < 8; d++) o[i][d] += __shfl_xor(o[i][d], 32);
    }

    // one partial per wave per row; lanes 0..15 of each wave write
    if ((t & 48) == 0) {
      const int w = t >> 6;
      #pragma unroll
      for (int i = 0; i < 4; i++) {
        float* ps = &Ps[(size_t)(w*64 + 4*rg + i) * 10];
        ps[0] = M; ps[1] = l[i];
        #pragma unroll
        for (int d = 0; d < 8; d++) ps[2 + d] = o[i][d];
      }
    }
    __syncthreads();

    // cross-wave: general M-aware merge of 4 partials, normalize, store
    if (t < 64) {
      float Mx = NEG, L = 0.f;
      float O8[8] = {0,0,0,0,0,0,0,0};
      #pragma unroll
      for (int ww = 0; ww < 4; ww++) {
        const float* ps = &Ps[(size_t)(ww*64 + t) * 10];
        const float mo = ps[0], lo = ps[1];
        const float mm = fmaxf(Mx, mo);
        const float a1 = __builtin_amdgcn_exp2f(Mx - mm);
        const float a2 = __builtin_amdgcn_exp2f(mo - mm);
        L = L*a1 + lo*a2;
        #pragma unroll
        for (int d = 0; d < 8; d++) O8[d] = O8[d]*a1 + ps[2 + d]*a2;
        Mx = mm;
      }
      const float inv = 1.0f / L;
      const int qrow = qb*64 + t;
      float* dst = O + ((size_t)b*SS + qrow)*DVV + h*DHH;
      float4 w0, w1;
      w0.x = O8[0]*inv; w0.y = O8[1]*inv; w0.z = O8[2]*inv; w0.w = O8[3]*inv;
      w1.x = O8[4]*inv; w1.y = O8[5]*inv; w1.z = O8[6]*inv; w1.w = O8[7]*inv;
      *(float4*)dst = w0;
      *(float4*)(dst + 4) = w1;
    }
    // no trailing barrier needed: next pass touches Ks/Vs (not Ps) before its
    // first kt-barrier, and all compute reads of Ks/Vs ended before the Ps
    // barrier above.
  }
}

// ---------------- Kernel C: output projection, register-tiled GEMM --------
// out[row,e] = sum_d O[row,d]*Wo[d,e] + bo[e]; grid (8192/64, 512/128), block 256.
// (unchanged)
__global__ __launch_bounds__(256)
void outproj_kernel(const float* __restrict__ Oin, const float* __restrict__ Wo,
                    const float* __restrict__ bo, float* __restrict__ out)
{
  __shared__ float Os[64][68];   // [k][row] transposed
  int t = threadIdx.x;
  int row0 = blockIdx.x * 64;
  int col0 = blockIdx.y * 128;

  {
    int row = t >> 2;
    #pragma unroll
    for (int it = 0; it < 4; it++) {
      int kq = 4*it + (t & 3);
      float4 vv = *(const float4*)(Oin + (size_t)(row0+row)*DVV + 4*kq);
      Os[4*kq+0][row] = vv.x;
      Os[4*kq+1][row] = vv.y;
      Os[4*kq+2][row] = vv.z;
      Os[4*kq+3][row] = vv.w;
    }
  }
  __syncthreads();

  int rg = t >> 5;               // 0..7 -> rows 8*rg..8*rg+7
  int tc = t & 31;               // cols col0 + 4*tc .. +3
  const float* wp = Wo + col0 + 4*tc;
  float4 b4 = *(const float4*)(bo + col0 + 4*tc);

  float acc[8][4];
  #pragma unroll
  for (int r = 0; r < 8; r++) {
    acc[r][0] = b4.x; acc[r][1] = b4.y; acc[r][2] = b4.z; acc[r][3] = b4.w;
  }

  #pragma unroll 8
  for (int k = 0; k < DVV; k++) {
    float4 w = *(const float4*)(wp + (size_t)k*EE);   // coalesced, L2-hot
    float xr[8];
    *(float4*)&xr[0] = *(const float4*)&Os[k][8*rg];
    *(float4*)&xr[4] = *(const float4*)&Os[k][8*rg + 4];
    #pragma unroll
    for (int r = 0; r < 8; r++) {
      acc[r][0] += xr[r]*w.x;
      acc[r][1] += xr[r]*w.y;
      acc[r][2] += xr[r]*w.z;
      acc[r][3] += xr[r]*w.w;
    }
  }

  #pragma unroll
  for (int r = 0; r < 8; r++) {
    int row = row0 + 8*rg + r;
    float4 vv; vv.x = acc[r][0]; vv.y = acc[r][1]; vv.z = acc[r][2]; vv.w = acc[r][3];
    *(float4*)(out + (size_t)row*EE + col0 + 4*tc) = vv;
  }
}

extern "C" void kernel_launch(void* const* d_in, const int* in_sizes, int n_in,
                              void* d_out, int out_size, void* d_ws, size_t ws_size,
                              hipStream_t stream) {
  // Size-based input identification: q/k/v=4194304, Wq/Wk/Wv/Wo=32768 in dict
  // order, bo=512. padding_mask (16777216) / decoder_mask (1) skipped.
  const void* qkv[3] = {nullptr, nullptr, nullptr};
  const void* Wlist[4] = {nullptr, nullptr, nullptr, nullptr};
  const void* bo = nullptr;
  int nqkv = 0, nw = 0;
  for (int i = 0; i < n_in; i++) {
    int sz = in_sizes[i];
    if (sz == BB*SS*EE)            { if (nqkv < 3) qkv[nqkv] = d_in[i]; nqkv++; }
    else if (sz == HH*EE*DHH)      { if (nw < 4) Wlist[nw] = d_in[i]; nw++; }
    else if (sz == EE)             { bo = d_in[i]; }
  }
  float* out = (float*)d_out;   // reference output dtype is float32

  // workspace (f32): Qp/Kp/Vp [B,H,S,8] (2MB each), O [B,S,64] (2MB)
  float* Qp = (float*)d_ws;
  float* Kp = Qp + (size_t)BB*HH*SS*DHH;
  float* Vp = Kp + (size_t)BB*HH*SS*DHH;
  float* O  = Vp + (size_t)BB*HH*SS*DHH;

  dim3 gA(BB*SS/64, 3, 1);
  proj_kernel<<<gA, 256, 0, stream>>>((const float*)qkv[0], (const float*)qkv[1],
                                      (const float*)qkv[2],
                                      (const float*)Wlist[0], (const float*)Wlist[1],
                                      (const float*)Wlist[2], Qp, Kp, Vp);

  dim3 gB(16, HH, BB);
  attn_kernel<<<gB, 256, 0, stream>>>(Qp, Kp, Vp, O);

  dim3 gC(BB*SS/64, EE/128, 1);
  outproj_kernel<<<gC, 256, 0, stream>>>(O, (const float*)Wlist[3],
                                         (const float*)bo, out);
}